// Round 3
// baseline (402.686 us; speedup 1.0000x reference)
//
#include <hip/hip_runtime.h>

#define NNODES 50000
#define NEDGES 800000
#define NCHUNK 13   // src chunk = src >> 12 (4096 nodes/chunk)

typedef __attribute__((ext_vector_type(8))) short short8;
typedef __attribute__((ext_vector_type(4))) float floatx4;

// async global->LDS, 16B per lane (emits global_load_lds_dwordx4)
__device__ __forceinline__ void async16(const void* g, void* l) {
    __builtin_amdgcn_global_load_lds(
        (const __attribute__((address_space(1))) unsigned int*)g,
        (__attribute__((address_space(3))) unsigned int*)l, 16, 0, 0);
}

__device__ __forceinline__ void split_bf16(float v, short& hi, short& lo) {
    unsigned u = __float_as_uint(v);
    unsigned hu = u & 0xffff0000u;
    hi = (short)(hu >> 16);
    float r = v - __uint_as_float(hu);
    lo = (short)(__float_as_uint(r) >> 16);
}

// ---------------- CSR build (chunk-sorted rows) ----------------

__global__ void k_count2(const int* __restrict__ src, const int* __restrict__ dst,
                         int* __restrict__ cnt2) {
    int e = blockIdx.x * 256 + threadIdx.x;
    if (e < NEDGES) atomicAdd(&cnt2[dst[e] * NCHUNK + (src[e] >> 12)], 1);
}

__global__ void k_rowsum(const int* __restrict__ cnt2, int* __restrict__ counts,
                         float* __restrict__ dinv) {
    int n = blockIdx.x * 256 + threadIdx.x;
    if (n < NNODES) {
        int s = 0;
#pragma unroll
        for (int c = 0; c < NCHUNK; c++) s += cnt2[n * NCHUNK + c];
        counts[n] = s;
        dinv[n] = rsqrtf((float)s + 1.0f);
    }
}

__global__ void k_scan1(const int* __restrict__ counts, int* __restrict__ rowptr,
                        int* __restrict__ bsum) {
    __shared__ int s[256];
    int t = threadIdx.x, i = blockIdx.x * 256 + t;
    int v = (i < NNODES) ? counts[i] : 0;
    s[t] = v; __syncthreads();
    for (int o = 1; o < 256; o <<= 1) {
        int x = (t >= o) ? s[t - o] : 0;
        __syncthreads();
        s[t] += x;
        __syncthreads();
    }
    if (i < NNODES) rowptr[i] = s[t] - v;
    if (t == 255) bsum[blockIdx.x] = s[255];
}

__global__ void k_scan2(int* bsum, int nb) {
    __shared__ int s[256];
    int t = threadIdx.x;
    int v = (t < nb) ? bsum[t] : 0;
    s[t] = v; __syncthreads();
    for (int o = 1; o < 256; o <<= 1) {
        int x = (t >= o) ? s[t - o] : 0;
        __syncthreads();
        s[t] += x;
        __syncthreads();
    }
    if (t < nb) bsum[t] = s[t] - v;
}

__global__ void k_scan3(int* __restrict__ rowptr, const int* __restrict__ bsum) {
    int t = threadIdx.x, b = blockIdx.x, i = b * 256 + t;
    if (i < NNODES) rowptr[i] += bsum[b];
    if (i == 0) rowptr[NNODES] = NEDGES;
}

__global__ void k_cursor2(const int* __restrict__ rowptr, const int* __restrict__ cnt2,
                          int* __restrict__ cursor2) {
    int n = blockIdx.x * 256 + threadIdx.x;
    if (n < NNODES) {
        int base = rowptr[n];
#pragma unroll
        for (int c = 0; c < NCHUNK; c++) {
            cursor2[n * NCHUNK + c] = base;
            base += cnt2[n * NCHUNK + c];
        }
    }
}

__global__ void k_bucket2(const int* __restrict__ src, const int* __restrict__ dst,
                          int* cursor2, int* __restrict__ ssrc) {
    int e = blockIdx.x * 256 + threadIdx.x;
    if (e < NEDGES) {
        int s = src[e], d = dst[e];
        int p = atomicAdd(&cursor2[d * NCHUNK + (s >> 12)], 1);
        ssrc[p] = s;
    }
}

// ---------------- weight / input prep ----------------

// W (K x F fp32) -> Wt hi/lo (F x K bf16)
__global__ void k_wprep(const float* __restrict__ W, short* __restrict__ Wth,
                        short* __restrict__ Wtl, int K, int F) {
    int id = blockIdx.x * 256 + threadIdx.x;
    if (id >= K * F) return;
    int f = id / K, k = id - f * K;
    short h, l;
    split_bf16(W[(size_t)k * F + f], h, l);
    Wth[id] = h;
    Wtl[id] = l;
}

// x (fp32) -> hi/lo bf16, elementwise (float4 per thread)
__global__ void k_split(const float* __restrict__ x, short* __restrict__ xh,
                        short* __restrict__ xl, int n4) {
    int i = blockIdx.x * 256 + threadIdx.x;
    if (i >= n4) return;
    float4 v = ((const float4*)x)[i];
    short4 h4, l4;
    split_bf16(v.x, h4.x, l4.x);
    split_bf16(v.y, h4.y, l4.y);
    split_bf16(v.z, h4.z, l4.z);
    split_bf16(v.w, h4.w, l4.w);
    *(short4*)&xh[i * 4] = h4;
    *(short4*)&xl[i * 4] = l4;
}

// ---------------- GEMM: G = (A @ W) * dinv[row], split-bf16 MFMA ----------
// A as hi/lo bf16 arrays (M x K). B = W^T hi/lo (F x K). G fp32 (M x F).
// BM=64, BK=64, BN=F. 256 threads = 4 waves; wave w -> rows w*16..w*16+15.
// m97-style: global_load_lds 16B staging, single LDS buffer, 2 barriers.

template <int BN>
__global__ __launch_bounds__(256) void k_gemm2(
    const short* __restrict__ Ah, const short* __restrict__ Al,
    const short* __restrict__ Bh, const short* __restrict__ Bl,
    const float* __restrict__ dinv, float* __restrict__ G, int M, int K) {
    constexpr int BM = 64, BK = 64;
    constexpr int NT = BN / 16;
    __shared__ __align__(16) short sAh[BM * BK], sAl[BM * BK];
    __shared__ __align__(16) short sBh[BN * BK], sBl[BN * BK];

    const int tid = threadIdx.x, lane = tid & 63, w = tid >> 6;
    const int row0 = blockIdx.x * BM;
    const int lr = lane >> 3;          // row within 8-row issue group
    const int lc = (lane & 7) * 8;     // bf16 col (16B granules)
    const int fr = lane & 15, fq = lane >> 4;

    floatx4 acc[NT] = {};

    for (int k0 = 0; k0 < K; k0 += BK) {
        // A tile: 8 issues hi + 8 lo (8 rows x 128B each); wave w -> j=w*2+{0,1}
#pragma unroll
        for (int jj = 0; jj < 2; jj++) {
            int j = w * 2 + jj;
            int r = j * 8 + lr;
            int grow = row0 + r;
            if (grow >= M) grow = M - 1;            // clamp: pad rows discarded
            size_t go = (size_t)grow * K + k0 + lc;
            async16(&Ah[go], &sAh[r * BK + lc]);
            async16(&Al[go], &sAl[r * BK + lc]);
        }
        // B tile: BN/8 issues hi + lo
#pragma unroll
        for (int jj = 0; jj < BN / 32; jj++) {
            int j = w * (BN / 32) + jj;
            int r = j * 8 + lr;
            size_t go = (size_t)r * K + k0 + lc;
            async16(&Bh[go], &sBh[r * BK + lc]);
            async16(&Bl[go], &sBl[r * BK + lc]);
        }
        __syncthreads();

#pragma unroll
        for (int ks = 0; ks < 2; ks++) {
            short8 ah = *(const short8*)&sAh[(w * 16 + fr) * BK + ks * 32 + fq * 8];
            short8 al = *(const short8*)&sAl[(w * 16 + fr) * BK + ks * 32 + fq * 8];
#pragma unroll
            for (int nt = 0; nt < NT; nt++) {
                short8 bh = *(const short8*)&sBh[(nt * 16 + fr) * BK + ks * 32 + fq * 8];
                short8 bl = *(const short8*)&sBl[(nt * 16 + fr) * BK + ks * 32 + fq * 8];
                acc[nt] = __builtin_amdgcn_mfma_f32_16x16x32_bf16(ah, bh, acc[nt], 0, 0, 0);
                acc[nt] = __builtin_amdgcn_mfma_f32_16x16x32_bf16(ah, bl, acc[nt], 0, 0, 0);
                acc[nt] = __builtin_amdgcn_mfma_f32_16x16x32_bf16(al, bh, acc[nt], 0, 0, 0);
            }
        }
        __syncthreads();
    }

#pragma unroll
    for (int rr = 0; rr < 4; rr++) {
        int grow = row0 + w * 16 + fq * 4 + rr;
        if (grow < M) {
            float dv = dinv[grow];
#pragma unroll
            for (int nt = 0; nt < NT; nt++)
                G[(size_t)grow * BN + nt * 16 + fr] = acc[nt][rr] * dv;
        }
    }
}

// ---------------- Aggregation (pull, rows chunk-sorted by src) -----------
// res = dinv[n]*(sum_e g[ssrc[e]] + g[n]) + b ; optional relu.
// writebf=1 -> emit bf16 hi/lo (next GEMM input); else fp32 out.

__global__ __launch_bounds__(256) void k_agg(const float* __restrict__ g,
                                             const int* __restrict__ ssrc,
                                             const int* __restrict__ rowptr,
                                             const float* __restrict__ dinv,
                                             const float* __restrict__ bias,
                                             float* __restrict__ outf,
                                             short* __restrict__ oh,
                                             short* __restrict__ ol,
                                             int F, int lgF4, int relu, int writebf) {
    int gid = blockIdx.x * 256 + threadIdx.x;
    int F4 = F >> 2;
    int n = gid >> lgF4;
    if (n >= NNODES) return;
    int c4 = gid & (F4 - 1);
    const float4* gp = (const float4*)g;

    float4 a0 = gp[(size_t)n * F4 + c4];  // self term
    float4 a1 = make_float4(0.f, 0.f, 0.f, 0.f);
    float4 a2 = make_float4(0.f, 0.f, 0.f, 0.f);
    float4 a3 = make_float4(0.f, 0.f, 0.f, 0.f);
    int e0 = rowptr[n], e1 = rowptr[n + 1];
    int e = e0;
    for (; e + 4 <= e1; e += 4) {
        int s0 = ssrc[e], s1 = ssrc[e + 1], s2 = ssrc[e + 2], s3 = ssrc[e + 3];
        float4 v0 = gp[(size_t)s0 * F4 + c4];
        float4 v1 = gp[(size_t)s1 * F4 + c4];
        float4 v2 = gp[(size_t)s2 * F4 + c4];
        float4 v3 = gp[(size_t)s3 * F4 + c4];
        a0.x += v0.x; a0.y += v0.y; a0.z += v0.z; a0.w += v0.w;
        a1.x += v1.x; a1.y += v1.y; a1.z += v1.z; a1.w += v1.w;
        a2.x += v2.x; a2.y += v2.y; a2.z += v2.z; a2.w += v2.w;
        a3.x += v3.x; a3.y += v3.y; a3.z += v3.z; a3.w += v3.w;
    }
    for (; e < e1; e++) {
        int s = ssrc[e];
        float4 v = gp[(size_t)s * F4 + c4];
        a0.x += v.x; a0.y += v.y; a0.z += v.z; a0.w += v.w;
    }
    float4 acc = make_float4(a0.x + a1.x + a2.x + a3.x,
                             a0.y + a1.y + a2.y + a3.y,
                             a0.z + a1.z + a2.z + a3.z,
                             a0.w + a1.w + a2.w + a3.w);
    float dv = dinv[n];
    float4 bv = *(const float4*)&bias[c4 * 4];
    float4 o = make_float4(acc.x * dv + bv.x, acc.y * dv + bv.y,
                           acc.z * dv + bv.z, acc.w * dv + bv.w);
    if (relu) {
        o.x = fmaxf(o.x, 0.f); o.y = fmaxf(o.y, 0.f);
        o.z = fmaxf(o.z, 0.f); o.w = fmaxf(o.w, 0.f);
    }
    if (writebf) {
        short4 h4, l4;
        split_bf16(o.x, h4.x, l4.x);
        split_bf16(o.y, h4.y, l4.y);
        split_bf16(o.z, h4.z, l4.z);
        split_bf16(o.w, h4.w, l4.w);
        *(short4*)&oh[(size_t)n * F + c4 * 4] = h4;
        *(short4*)&ol[(size_t)n * F + c4 * 4] = l4;
    } else {
        *(float4*)&outf[(size_t)n * F + c4 * 4] = o;
    }
}

// ---------------- launch ----------------

static inline size_t align256(size_t x) { return (x + 255) & ~(size_t)255; }

extern "C" void kernel_launch(void* const* d_in, const int* in_sizes, int n_in,
                              void* d_out, int out_size, void* d_ws, size_t ws_size,
                              hipStream_t stream) {
    const float* x  = (const float*)d_in[0];
    const int*   ei = (const int*)d_in[1];
    const float* W0 = (const float*)d_in[2];
    const float* b0 = (const float*)d_in[3];
    const float* W1 = (const float*)d_in[4];
    const float* b1 = (const float*)d_in[5];
    const float* W2 = (const float*)d_in[6];
    const float* b2 = (const float*)d_in[7];
    float* out = (float*)d_out;

    const int* src = ei;
    const int* dst = ei + NEDGES;

    char* w = (char*)d_ws;
    size_t off = 0;
    float* dinv   = (float*)(w + off); off = align256(off + NNODES * 4);
    int* counts   = (int*)(w + off);   off = align256(off + NNODES * 4);
    int* rowptr   = (int*)(w + off);   off = align256(off + (NNODES + 1) * 4);
    int* bsum     = (int*)(w + off);   off = align256(off + 256 * 4);
    int* cnt2     = (int*)(w + off);   off = align256(off + (size_t)NNODES * NCHUNK * 4);
    int* cursor2  = (int*)(w + off);   off = align256(off + (size_t)NNODES * NCHUNK * 4);
    int* ssrc     = (int*)(w + off);   off = align256(off + NEDGES * 4);
    short* W0h    = (short*)(w + off); off = align256(off + 256 * 128 * 2);
    short* W0l    = (short*)(w + off); off = align256(off + 256 * 128 * 2);
    short* W1h    = (short*)(w + off); off = align256(off + 128 * 128 * 2);
    short* W1l    = (short*)(w + off); off = align256(off + 128 * 128 * 2);
    short* W2h    = (short*)(w + off); off = align256(off + 128 * 64 * 2);
    short* W2l    = (short*)(w + off); off = align256(off + 128 * 64 * 2);
    short* xh     = (short*)(w + off); off = align256(off + (size_t)NNODES * 256 * 2);
    short* xl     = (short*)(w + off); off = align256(off + (size_t)NNODES * 256 * 2);
    short* ph     = (short*)(w + off); off = align256(off + (size_t)NNODES * 128 * 2);
    short* pl     = (short*)(w + off); off = align256(off + (size_t)NNODES * 128 * 2);
    float* g      = (float*)(w + off); off = align256(off + (size_t)NNODES * 128 * 4);

    const int EB = (NEDGES + 255) / 256;
    const int NB = (NNODES + 255) / 256;

    // prep (independent of CSR)
    k_wprep<<<(256 * 128 + 255) / 256, 256, 0, stream>>>(W0, W0h, W0l, 256, 128);
    k_wprep<<<(128 * 128 + 255) / 256, 256, 0, stream>>>(W1, W1h, W1l, 128, 128);
    k_wprep<<<(128 * 64 + 255) / 256, 256, 0, stream>>>(W2, W2h, W2l, 128, 64);
    k_split<<<(NNODES * 64 + 255) / 256, 256, 0, stream>>>(x, xh, xl, NNODES * 64);

    // CSR build, rows bucketed by src chunk
    hipMemsetAsync(cnt2, 0, (size_t)NNODES * NCHUNK * 4, stream);
    k_count2<<<EB, 256, 0, stream>>>(src, dst, cnt2);
    k_rowsum<<<NB, 256, 0, stream>>>(cnt2, counts, dinv);
    k_scan1<<<NB, 256, 0, stream>>>(counts, rowptr, bsum);
    k_scan2<<<1, 256, 0, stream>>>(bsum, NB);
    k_scan3<<<NB, 256, 0, stream>>>(rowptr, bsum);
    k_cursor2<<<NB, 256, 0, stream>>>(rowptr, cnt2, cursor2);
    k_bucket2<<<EB, 256, 0, stream>>>(src, dst, cursor2, ssrc);

    const int MB = (NNODES + 63) / 64;   // 782

    // layer 0
    k_gemm2<128><<<MB, 256, 0, stream>>>(xh, xl, W0h, W0l, dinv, g, NNODES, 256);
    k_agg<<<(NNODES * 32) / 256, 256, 0, stream>>>(g, ssrc, rowptr, dinv, b0,
                                                   (float*)nullptr, ph, pl, 128, 5, 1, 1);
    // layer 1
    k_gemm2<128><<<MB, 256, 0, stream>>>(ph, pl, W1h, W1l, dinv, g, NNODES, 128);
    k_agg<<<(NNODES * 32) / 256, 256, 0, stream>>>(g, ssrc, rowptr, dinv, b1,
                                                   (float*)nullptr, ph, pl, 128, 5, 1, 1);
    // layer 2
    k_gemm2<64><<<MB, 256, 0, stream>>>(ph, pl, W2h, W2l, dinv, g, NNODES, 128);
    k_agg<<<(NNODES * 16) / 256, 256, 0, stream>>>(g, ssrc, rowptr, dinv, b2,
                                                   out, (short*)nullptr, (short*)nullptr,
                                                   64, 4, 0, 0);
    (void)in_sizes; (void)n_in; (void)out_size; (void)ws_size;
}

// Round 4
// 334.373 us; speedup vs baseline: 1.2043x; 1.2043x over previous
//
#include <hip/hip_runtime.h>

#define NNODES 50000
#define NEDGES 800000

typedef __attribute__((ext_vector_type(8))) short short8;
typedef __attribute__((ext_vector_type(4))) float floatx4;
typedef __attribute__((ext_vector_type(4))) _Float16 f16x4;

// async global->LDS, 16B per lane (global_load_lds_dwordx4).
// LDS dest MUST be wave-uniform base + lane*16.
__device__ __forceinline__ void async16(const void* g, void* l) {
    __builtin_amdgcn_global_load_lds(
        (const __attribute__((address_space(1))) unsigned int*)g,
        (__attribute__((address_space(3))) unsigned int*)l, 16, 0, 0);
}

__device__ __forceinline__ void split_bf16(float v, short& hi, short& lo) {
    unsigned u = __float_as_uint(v);
    unsigned hu = u & 0xffff0000u;
    hi = (short)(hu >> 16);
    float r = v - __uint_as_float(hu);
    lo = (short)(__float_as_uint(r) >> 16);
}

// ---------------- CSR build ----------------

__global__ void k_count(const int* __restrict__ dst, int* __restrict__ counts) {
    int e = blockIdx.x * 256 + threadIdx.x;
    if (e < NEDGES) atomicAdd(&counts[dst[e]], 1);
}

// scan1 also emits dinv
__global__ void k_scan1(const int* __restrict__ counts, int* __restrict__ rowptr,
                        int* __restrict__ bsum, float* __restrict__ dinv) {
    __shared__ int s[256];
    int t = threadIdx.x, i = blockIdx.x * 256 + t;
    int v = (i < NNODES) ? counts[i] : 0;
    if (i < NNODES) dinv[i] = rsqrtf((float)v + 1.0f);
    s[t] = v; __syncthreads();
    for (int o = 1; o < 256; o <<= 1) {
        int x = (t >= o) ? s[t - o] : 0;
        __syncthreads();
        s[t] += x;
        __syncthreads();
    }
    if (i < NNODES) rowptr[i] = s[t] - v;
    if (t == 255) bsum[blockIdx.x] = s[255];
}

__global__ void k_scan2(int* bsum, int nb) {
    __shared__ int s[256];
    int t = threadIdx.x;
    int v = (t < nb) ? bsum[t] : 0;
    s[t] = v; __syncthreads();
    for (int o = 1; o < 256; o <<= 1) {
        int x = (t >= o) ? s[t - o] : 0;
        __syncthreads();
        s[t] += x;
        __syncthreads();
    }
    if (t < nb) bsum[t] = s[t] - v;
}

__global__ void k_scan3(int* __restrict__ rowptr, const int* __restrict__ bsum,
                        int* __restrict__ cursor) {
    int t = threadIdx.x, b = blockIdx.x, i = b * 256 + t;
    if (i < NNODES) {
        int r = rowptr[i] + bsum[b];
        rowptr[i] = r;
        cursor[i] = r;
    }
    if (i == 0) rowptr[NNODES] = NEDGES;
}

__global__ void k_bucket(const int* __restrict__ src, const int* __restrict__ dst,
                         int* cursor, int* __restrict__ ssrc) {
    int e = blockIdx.x * 256 + threadIdx.x;
    if (e < NEDGES) {
        int d = dst[e];
        int p = atomicAdd(&cursor[d], 1);
        ssrc[p] = src[e];
    }
}

// ---------------- prep ----------------

// All three weights -> transposed hi/lo bf16 in one dispatch.
__global__ void k_wprep3(const float* __restrict__ W0, short* __restrict__ W0h,
                         short* __restrict__ W0l, const float* __restrict__ W1,
                         short* __restrict__ W1h, short* __restrict__ W1l,
                         const float* __restrict__ W2, short* __restrict__ W2h,
                         short* __restrict__ W2l) {
    int id = blockIdx.x * 256 + threadIdx.x;
    const float* W; short *Wh, *Wl; int K, F;
    if (id < 32768) { W = W0; Wh = W0h; Wl = W0l; K = 256; F = 128; }
    else if (id < 49152) { id -= 32768; W = W1; Wh = W1h; Wl = W1l; K = 128; F = 128; }
    else if (id < 57344) { id -= 49152; W = W2; Wh = W2h; Wl = W2l; K = 128; F = 64; }
    else return;
    int f = id / K, k = id - f * K;
    short h, l;
    split_bf16(W[(size_t)k * F + f], h, l);
    Wh[id] = h;
    Wl[id] = l;
}

// x fp32 -> hi/lo bf16 (float4/thread); also zeroes counts.
__global__ void k_split(const float* __restrict__ x, short* __restrict__ xh,
                        short* __restrict__ xl, int* __restrict__ counts, int n4) {
    int i = blockIdx.x * 256 + threadIdx.x;
    if (i < NNODES) counts[i] = 0;
    if (i >= n4) return;
    float4 v = ((const float4*)x)[i];
    short4 h4, l4;
    split_bf16(v.x, h4.x, l4.x);
    split_bf16(v.y, h4.y, l4.y);
    split_bf16(v.z, h4.z, l4.z);
    split_bf16(v.w, h4.w, l4.w);
    *(short4*)&xh[i * 4] = h4;
    *(short4*)&xl[i * 4] = l4;
}

// ---------------- GEMM: g16 = fp16((A @ W) * dinv[row]) ------------------
// A hi/lo bf16 (M x K), B = W^T hi/lo (BN x K), out fp16 (M x BN).
// BM=64, BK=64, 256 thr = 4 waves, wave w -> rows w*16..w*16+15.
// XOR swizzle: LDS[r][c'] holds global k-block c'^(r&7) (16B blocks),
// so staging keeps dest = base + lane*16 while fragment reads spread banks.

template <int BN>
__global__ __launch_bounds__(256) void k_gemm2(
    const short* __restrict__ Ah, const short* __restrict__ Al,
    const short* __restrict__ Bh, const short* __restrict__ Bl,
    const float* __restrict__ dinv, _Float16* __restrict__ g16,
    int M, int K) {
    constexpr int BM = 64, BK = 64;
    constexpr int NT = BN / 16;
    __shared__ __align__(16) short sAh[BM * BK], sAl[BM * BK];
    __shared__ __align__(16) short sBh[BN * BK], sBl[BN * BK];

    const int tid = threadIdx.x, lane = tid & 63, w = tid >> 6;
    const int row0 = blockIdx.x * BM;
    const int lr = lane >> 3;                 // row within 8-row group
    const int lz = lane & 7;                  // 16B k-block slot
    const int swz = (lz ^ lr) * 8;            // swizzled global k offset (shorts)
    const int fr = lane & 15, fq = lane >> 4;

    floatx4 acc[NT] = {};

    for (int k0 = 0; k0 < K; k0 += BK) {
        // A tile: wave w stages rows j*8..j*8+7 for j=w*2+{0,1}
#pragma unroll
        for (int jj = 0; jj < 2; jj++) {
            int j = w * 2 + jj;
            int grow = row0 + j * 8 + lr;
            if (grow >= M) grow = M - 1;       // dup row, discarded in epilogue
            size_t go = (size_t)grow * K + k0 + swz;
            async16(&Ah[go], &sAh[j * 8 * BK + lane * 8]);
            async16(&Al[go], &sAl[j * 8 * BK + lane * 8]);
        }
        // B tile
#pragma unroll
        for (int jj = 0; jj < BN / 32; jj++) {
            int j = w * (BN / 32) + jj;
            size_t go = (size_t)(j * 8 + lr) * K + k0 + swz;
            async16(&Bh[go], &sBh[j * 8 * BK + lane * 8]);
            async16(&Bl[go], &sBl[j * 8 * BK + lane * 8]);
        }
        __syncthreads();

#pragma unroll
        for (int ks = 0; ks < 2; ks++) {
            int R = w * 16 + fr;
            int ca = ((ks * 4 + fq) ^ (R & 7)) * 8;
            short8 ah = *(const short8*)&sAh[R * BK + ca];
            short8 al = *(const short8*)&sAl[R * BK + ca];
#pragma unroll
            for (int nt = 0; nt < NT; nt++) {
                int n = nt * 16 + fr;
                int cb = ((ks * 4 + fq) ^ (n & 7)) * 8;
                short8 bh = *(const short8*)&sBh[n * BK + cb];
                short8 bl = *(const short8*)&sBl[n * BK + cb];
                acc[nt] = __builtin_amdgcn_mfma_f32_16x16x32_bf16(ah, bh, acc[nt], 0, 0, 0);
                acc[nt] = __builtin_amdgcn_mfma_f32_16x16x32_bf16(ah, bl, acc[nt], 0, 0, 0);
                acc[nt] = __builtin_amdgcn_mfma_f32_16x16x32_bf16(al, bh, acc[nt], 0, 0, 0);
            }
        }
        __syncthreads();
    }

#pragma unroll
    for (int rr = 0; rr < 4; rr++) {
        int grow = row0 + w * 16 + fq * 4 + rr;
        if (grow < M) {
            float dv = dinv[grow];
#pragma unroll
            for (int nt = 0; nt < NT; nt++)
                g16[(size_t)grow * BN + nt * 16 + fr] =
                    (_Float16)(acc[nt][rr] * dv);
        }
    }
}

// ---------------- Aggregation (pull, fp16 gathers) ----------------
// res = dinv[n]*(sum_e g[ssrc[e]] + g[n]) + b ; optional relu.
// writebf=1 -> emit bf16 hi/lo (next GEMM input); else fp32 out.

__global__ __launch_bounds__(256) void k_agg(const _Float16* __restrict__ g,
                                             const int* __restrict__ ssrc,
                                             const int* __restrict__ rowptr,
                                             const float* __restrict__ dinv,
                                             const float* __restrict__ bias,
                                             float* __restrict__ outf,
                                             short* __restrict__ oh,
                                             short* __restrict__ ol,
                                             int F, int lgF4, int relu, int writebf) {
    int gid = blockIdx.x * 256 + threadIdx.x;
    int F4 = F >> 2;
    int n = gid >> lgF4;
    if (n >= NNODES) return;
    int c4 = gid & (F4 - 1);
    const f16x4* gp = (const f16x4*)g;

    f16x4 sv = gp[(size_t)n * F4 + c4];       // self term
    float4 a0 = make_float4((float)sv[0], (float)sv[1], (float)sv[2], (float)sv[3]);
    float4 a1 = make_float4(0.f, 0.f, 0.f, 0.f);
    float4 a2 = make_float4(0.f, 0.f, 0.f, 0.f);
    float4 a3 = make_float4(0.f, 0.f, 0.f, 0.f);
    int e0 = rowptr[n], e1 = rowptr[n + 1];
    int e = e0;
    for (; e + 4 <= e1; e += 4) {
        int s0 = ssrc[e], s1 = ssrc[e + 1], s2 = ssrc[e + 2], s3 = ssrc[e + 3];
        f16x4 v0 = gp[(size_t)s0 * F4 + c4];
        f16x4 v1 = gp[(size_t)s1 * F4 + c4];
        f16x4 v2 = gp[(size_t)s2 * F4 + c4];
        f16x4 v3 = gp[(size_t)s3 * F4 + c4];
        a0.x += (float)v0[0]; a0.y += (float)v0[1]; a0.z += (float)v0[2]; a0.w += (float)v0[3];
        a1.x += (float)v1[0]; a1.y += (float)v1[1]; a1.z += (float)v1[2]; a1.w += (float)v1[3];
        a2.x += (float)v2[0]; a2.y += (float)v2[1]; a2.z += (float)v2[2]; a2.w += (float)v2[3];
        a3.x += (float)v3[0]; a3.y += (float)v3[1]; a3.z += (float)v3[2]; a3.w += (float)v3[3];
    }
    for (; e < e1; e++) {
        int s = ssrc[e];
        f16x4 v = gp[(size_t)s * F4 + c4];
        a0.x += (float)v[0]; a0.y += (float)v[1]; a0.z += (float)v[2]; a0.w += (float)v[3];
    }
    float4 acc = make_float4(a0.x + a1.x + a2.x + a3.x,
                             a0.y + a1.y + a2.y + a3.y,
                             a0.z + a1.z + a2.z + a3.z,
                             a0.w + a1.w + a2.w + a3.w);
    float dv = dinv[n];
    float4 bv = *(const float4*)&bias[c4 * 4];
    float4 o = make_float4(acc.x * dv + bv.x, acc.y * dv + bv.y,
                           acc.z * dv + bv.z, acc.w * dv + bv.w);
    if (relu) {
        o.x = fmaxf(o.x, 0.f); o.y = fmaxf(o.y, 0.f);
        o.z = fmaxf(o.z, 0.f); o.w = fmaxf(o.w, 0.f);
    }
    if (writebf) {
        short4 h4, l4;
        split_bf16(o.x, h4.x, l4.x);
        split_bf16(o.y, h4.y, l4.y);
        split_bf16(o.z, h4.z, l4.z);
        split_bf16(o.w, h4.w, l4.w);
        *(short4*)&oh[(size_t)n * F + c4 * 4] = h4;
        *(short4*)&ol[(size_t)n * F + c4 * 4] = l4;
    } else {
        *(float4*)&outf[(size_t)n * F + c4 * 4] = o;
    }
}

// ---------------- launch ----------------

static inline size_t align256(size_t x) { return (x + 255) & ~(size_t)255; }

extern "C" void kernel_launch(void* const* d_in, const int* in_sizes, int n_in,
                              void* d_out, int out_size, void* d_ws, size_t ws_size,
                              hipStream_t stream) {
    const float* x  = (const float*)d_in[0];
    const int*   ei = (const int*)d_in[1];
    const float* W0 = (const float*)d_in[2];
    const float* b0 = (const float*)d_in[3];
    const float* W1 = (const float*)d_in[4];
    const float* b1 = (const float*)d_in[5];
    const float* W2 = (const float*)d_in[6];
    const float* b2 = (const float*)d_in[7];
    float* out = (float*)d_out;

    const int* src = ei;
    const int* dst = ei + NEDGES;

    char* w = (char*)d_ws;
    size_t off = 0;
    float* dinv   = (float*)(w + off); off = align256(off + NNODES * 4);
    int* counts   = (int*)(w + off);   off = align256(off + NNODES * 4);
    int* rowptr   = (int*)(w + off);   off = align256(off + (NNODES + 1) * 4);
    int* cursor   = (int*)(w + off);   off = align256(off + NNODES * 4);
    int* bsum     = (int*)(w + off);   off = align256(off + 256 * 4);
    int* ssrc     = (int*)(w + off);   off = align256(off + NEDGES * 4);
    short* W0h    = (short*)(w + off); off = align256(off + 256 * 128 * 2);
    short* W0l    = (short*)(w + off); off = align256(off + 256 * 128 * 2);
    short* W1h    = (short*)(w + off); off = align256(off + 128 * 128 * 2);
    short* W1l    = (short*)(w + off); off = align256(off + 128 * 128 * 2);
    short* W2h    = (short*)(w + off); off = align256(off + 128 * 64 * 2);
    short* W2l    = (short*)(w + off); off = align256(off + 128 * 64 * 2);
    short* xh     = (short*)(w + off); off = align256(off + (size_t)NNODES * 256 * 2);
    short* xl     = (short*)(w + off); off = align256(off + (size_t)NNODES * 256 * 2);
    short* ph     = (short*)(w + off); off = align256(off + (size_t)NNODES * 128 * 2);
    short* pl     = (short*)(w + off); off = align256(off + (size_t)NNODES * 128 * 2);
    _Float16* g16 = (_Float16*)(w + off); off = align256(off + (size_t)NNODES * 128 * 2);

    const int EB = (NEDGES + 255) / 256;
    const int NB = (NNODES + 255) / 256;

    // prep (also zeroes counts)
    k_wprep3<<<224, 256, 0, stream>>>(W0, W0h, W0l, W1, W1h, W1l, W2, W2h, W2l);
    k_split<<<(NNODES * 64 + 255) / 256, 256, 0, stream>>>(x, xh, xl, counts,
                                                           NNODES * 64);
    // CSR
    k_count<<<EB, 256, 0, stream>>>(dst, counts);
    k_scan1<<<NB, 256, 0, stream>>>(counts, rowptr, bsum, dinv);
    k_scan2<<<1, 256, 0, stream>>>(bsum, NB);
    k_scan3<<<NB, 256, 0, stream>>>(rowptr, bsum, cursor);
    k_bucket<<<EB, 256, 0, stream>>>(src, dst, cursor, ssrc);

    const int MB = (NNODES + 63) / 64;   // 782

    // layer 0
    k_gemm2<128><<<MB, 256, 0, stream>>>(xh, xl, W0h, W0l, dinv, g16, NNODES, 256);
    k_agg<<<(NNODES * 32) / 256, 256, 0, stream>>>(g16, ssrc, rowptr, dinv, b0,
                                                   (float*)nullptr, ph, pl, 128, 5, 1, 1);
    // layer 1
    k_gemm2<128><<<MB, 256, 0, stream>>>(ph, pl, W1h, W1l, dinv, g16, NNODES, 128);
    k_agg<<<(NNODES * 32) / 256, 256, 0, stream>>>(g16, ssrc, rowptr, dinv, b1,
                                                   (float*)nullptr, ph, pl, 128, 5, 1, 1);
    // layer 2
    k_gemm2<64><<<MB, 256, 0, stream>>>(ph, pl, W2h, W2l, dinv, g16, NNODES, 128);
    k_agg<<<(NNODES * 16) / 256, 256, 0, stream>>>(g16, ssrc, rowptr, dinv, b2,
                                                   out, (short*)nullptr, (short*)nullptr,
                                                   64, 4, 0, 0);
    (void)in_sizes; (void)n_in; (void)out_size; (void)ws_size;
}

// Round 5
// 277.228 us; speedup vs baseline: 1.4525x; 1.2061x over previous
//
#include <hip/hip_runtime.h>

#define NNODES 50000
#define NEDGES 800000
#define CHUNK 3125          // edges per P1/P2 block (256 blocks * 3125 = 800000)

typedef __attribute__((ext_vector_type(8))) short short8;
typedef __attribute__((ext_vector_type(4))) float floatx4;
typedef __attribute__((ext_vector_type(8))) _Float16 f16x8;

// async global->LDS, 16B per lane (global_load_lds_dwordx4).
// LDS dest MUST be wave-uniform base + lane*16.
__device__ __forceinline__ void async16(const void* g, void* l) {
    __builtin_amdgcn_global_load_lds(
        (const __attribute__((address_space(1))) unsigned int*)g,
        (__attribute__((address_space(3))) unsigned int*)l, 16, 0, 0);
}

__device__ __forceinline__ void split_bf16(float v, short& hi, short& lo) {
    unsigned u = __float_as_uint(v);
    unsigned hu = u & 0xffff0000u;
    hi = (short)(hu >> 16);
    float r = v - __uint_as_float(hu);
    lo = (short)(__float_as_uint(r) >> 16);
}

// ---------------- prep ----------------

// All three weights -> transposed hi/lo bf16 in one dispatch.
__global__ void k_wprep3(const float* __restrict__ W0, short* __restrict__ W0h,
                         short* __restrict__ W0l, const float* __restrict__ W1,
                         short* __restrict__ W1h, short* __restrict__ W1l,
                         const float* __restrict__ W2, short* __restrict__ W2h,
                         short* __restrict__ W2l) {
    int id = blockIdx.x * 256 + threadIdx.x;
    const float* W; short *Wh, *Wl; int K, F;
    if (id < 32768) { W = W0; Wh = W0h; Wl = W0l; K = 256; F = 128; }
    else if (id < 49152) { id -= 32768; W = W1; Wh = W1h; Wl = W1l; K = 128; F = 128; }
    else if (id < 57344) { id -= 49152; W = W2; Wh = W2h; Wl = W2l; K = 128; F = 64; }
    else return;
    int f = id / K, k = id - f * K;
    short h, l;
    split_bf16(W[(size_t)k * F + f], h, l);
    Wh[id] = h;
    Wl[id] = l;
}

// x fp32 -> hi/lo bf16 (8 floats/thread, 16B stores); also zeroes chist.
__global__ void k_split(const float* __restrict__ x, short* __restrict__ xh,
                        short* __restrict__ xl, int* __restrict__ chist, int n8) {
    int i = blockIdx.x * 256 + threadIdx.x;
    if (i < 256) chist[i] = 0;
    if (i >= n8) return;
    float4 v0 = ((const float4*)x)[i * 2];
    float4 v1 = ((const float4*)x)[i * 2 + 1];
    float va[8] = {v0.x, v0.y, v0.z, v0.w, v1.x, v1.y, v1.z, v1.w};
    short8 h8, l8;
#pragma unroll
    for (int j = 0; j < 8; j++) {
        short h, l;
        split_bf16(va[j], h, l);
        h8[j] = h; l8[j] = l;
    }
    *(short8*)&xh[i * 8] = h8;
    *(short8*)&xl[i * 8] = l8;
}

// ---------------- CSR build: two-level radix scatter ----------------

// P1: coarse histogram of dst>>8
__global__ __launch_bounds__(256) void k_p1(const int* __restrict__ dst,
                                            int* __restrict__ chist) {
    __shared__ int h[256];
    int t = threadIdx.x, b = blockIdx.x;
    h[t] = 0;
    __syncthreads();
    int e0 = b * CHUNK;
#pragma unroll
    for (int k = 0; k < 13; k++) {
        int o = k * 256 + t;
        if (o < CHUNK) atomicAdd(&h[dst[e0 + o] >> 8], 1);
    }
    __syncthreads();
    if (h[t]) atomicAdd(&chist[t], h[t]);
}

// coarse scan: chist -> coff (exclusive), init cursor, set rowptr[N]
__global__ void k_cscan(const int* __restrict__ chist, int* __restrict__ coff,
                        int* __restrict__ ccur, int* __restrict__ rowptr) {
    __shared__ int s[256];
    int t = threadIdx.x;
    int v = chist[t];
    s[t] = v; __syncthreads();
    for (int o = 1; o < 256; o <<= 1) {
        int x = (t >= o) ? s[t - o] : 0;
        __syncthreads();
        s[t] += x;
        __syncthreads();
    }
    int excl = s[t] - v;
    coff[t] = excl;
    ccur[t] = excl;
    if (t == 0) rowptr[NNODES] = NEDGES;
}

// P2: scatter packed (src | (dst&255)<<16) into coarse buckets.
__global__ __launch_bounds__(256) void k_p2(const int* __restrict__ src,
                                            const int* __restrict__ dst,
                                            int* ccur, unsigned* __restrict__ buck) {
    __shared__ int hist[256];
    __shared__ int base[256];
    int t = threadIdx.x, b = blockIdx.x;
    hist[t] = 0;
    __syncthreads();
    int e0 = b * CHUNK;
    int myb[13]; int myi[13]; unsigned pk[13];
#pragma unroll
    for (int k = 0; k < 13; k++) {
        int o = k * 256 + t;
        if (o < CHUNK) {
            int s = src[e0 + o], d = dst[e0 + o];
            int bin = d >> 8;
            myb[k] = bin;
            myi[k] = atomicAdd(&hist[bin], 1);
            pk[k] = (unsigned)s | ((unsigned)(d & 255) << 16);
        }
    }
    __syncthreads();
    base[t] = hist[t] ? atomicAdd(&ccur[t], hist[t]) : 0;
    __syncthreads();
#pragma unroll
    for (int k = 0; k < 13; k++) {
        int o = k * 256 + t;
        if (o < CHUNK) buck[base[myb[k]] + myi[k]] = pk[k];
    }
}

// P3: one block per coarse bucket. Exact counts/rowptr/dinv + final scatter.
__global__ __launch_bounds__(256) void k_p3(const unsigned* __restrict__ buck,
                                            const int* __restrict__ coff,
                                            const int* __restrict__ chist,
                                            int* __restrict__ rowptr,
                                            float* __restrict__ dinv,
                                            int* __restrict__ ssrc) {
    __shared__ int h[256], ex[256], cur[256];
    int t = threadIdx.x, b = blockIdx.x;
    int s0 = coff[b], S = chist[b];
    h[t] = 0;
    __syncthreads();
    for (int i = t; i < S; i += 256)
        atomicAdd(&h[(buck[s0 + i] >> 16) & 255], 1);
    __syncthreads();
    int v = h[t];
    ex[t] = v; __syncthreads();
    for (int o = 1; o < 256; o <<= 1) {
        int x = (t >= o) ? ex[t - o] : 0;
        __syncthreads();
        ex[t] += x;
        __syncthreads();
    }
    int excl = ex[t] - v;
    int n = b * 256 + t;
    if (n < NNODES) {
        rowptr[n] = s0 + excl;
        dinv[n] = rsqrtf((float)v + 1.0f);
    }
    cur[t] = excl;
    __syncthreads();
    for (int i = t; i < S; i += 256) {
        unsigned pk = buck[s0 + i];
        int dl = (pk >> 16) & 255;
        int p = atomicAdd(&cur[dl], 1);
        ssrc[s0 + p] = (int)(pk & 0xFFFFu);
    }
}

// ---------------- GEMM: g16 = fp16((A @ W) * dinv[row]) ------------------
// A hi/lo bf16 (M x K), B = W^T hi/lo (BN x K), out fp16 (M x BN).
// BM=64, BK=64, 256 thr = 4 waves; XOR-swizzled LDS (16B blocks) so the
// wave-uniform global_load_lds dest stays base+lane*16 while fragment
// reads spread across banks (2-way max).

template <int BN>
__global__ __launch_bounds__(256) void k_gemm2(
    const short* __restrict__ Ah, const short* __restrict__ Al,
    const short* __restrict__ Bh, const short* __restrict__ Bl,
    const float* __restrict__ dinv, _Float16* __restrict__ g16,
    int M, int K) {
    constexpr int BM = 64, BK = 64;
    constexpr int NT = BN / 16;
    __shared__ __align__(16) short sAh[BM * BK], sAl[BM * BK];
    __shared__ __align__(16) short sBh[BN * BK], sBl[BN * BK];

    const int tid = threadIdx.x, lane = tid & 63, w = tid >> 6;
    const int row0 = blockIdx.x * BM;
    const int lr = lane >> 3;
    const int lz = lane & 7;
    const int swz = (lz ^ lr) * 8;
    const int fr = lane & 15, fq = lane >> 4;

    floatx4 acc[NT] = {};

    for (int k0 = 0; k0 < K; k0 += BK) {
#pragma unroll
        for (int jj = 0; jj < 2; jj++) {
            int j = w * 2 + jj;
            int grow = row0 + j * 8 + lr;
            if (grow >= M) grow = M - 1;
            size_t go = (size_t)grow * K + k0 + swz;
            async16(&Ah[go], &sAh[j * 8 * BK + lane * 8]);
            async16(&Al[go], &sAl[j * 8 * BK + lane * 8]);
        }
#pragma unroll
        for (int jj = 0; jj < BN / 32; jj++) {
            int j = w * (BN / 32) + jj;
            size_t go = (size_t)(j * 8 + lr) * K + k0 + swz;
            async16(&Bh[go], &sBh[j * 8 * BK + lane * 8]);
            async16(&Bl[go], &sBl[j * 8 * BK + lane * 8]);
        }
        __syncthreads();

#pragma unroll
        for (int ks = 0; ks < 2; ks++) {
            int R = w * 16 + fr;
            int ca = ((ks * 4 + fq) ^ (R & 7)) * 8;
            short8 ah = *(const short8*)&sAh[R * BK + ca];
            short8 al = *(const short8*)&sAl[R * BK + ca];
#pragma unroll
            for (int nt = 0; nt < NT; nt++) {
                int n = nt * 16 + fr;
                int cb = ((ks * 4 + fq) ^ (n & 7)) * 8;
                short8 bh = *(const short8*)&sBh[n * BK + cb];
                short8 bl = *(const short8*)&sBl[n * BK + cb];
                acc[nt] = __builtin_amdgcn_mfma_f32_16x16x32_bf16(ah, bh, acc[nt], 0, 0, 0);
                acc[nt] = __builtin_amdgcn_mfma_f32_16x16x32_bf16(ah, bl, acc[nt], 0, 0, 0);
                acc[nt] = __builtin_amdgcn_mfma_f32_16x16x32_bf16(al, bh, acc[nt], 0, 0, 0);
            }
        }
        __syncthreads();
    }

#pragma unroll
    for (int rr = 0; rr < 4; rr++) {
        int grow = row0 + w * 16 + fq * 4 + rr;
        if (grow < M) {
            float dv = dinv[grow];
#pragma unroll
            for (int nt = 0; nt < NT; nt++)
                g16[(size_t)grow * BN + nt * 16 + fr] =
                    (_Float16)(acc[nt][rr] * dv);
        }
    }
}

// ---------------- Aggregation (pull, 16B fp16 gathers) ----------------
// res = dinv[n]*(sum_e g[ssrc[e]] + g[n]) + b ; optional relu.
// One thread per (node, 8-feature chunk).

__global__ __launch_bounds__(256) void k_agg(const _Float16* __restrict__ g,
                                             const int* __restrict__ ssrc,
                                             const int* __restrict__ rowptr,
                                             const float* __restrict__ dinv,
                                             const float* __restrict__ bias,
                                             float* __restrict__ outf,
                                             short* __restrict__ oh,
                                             short* __restrict__ ol,
                                             int F, int lgF8, int relu, int writebf) {
    int gid = blockIdx.x * 256 + threadIdx.x;
    int F8 = F >> 3;
    int n = gid >> lgF8;
    if (n >= NNODES) return;
    int c8 = gid & (F8 - 1);
    const f16x8* gp = (const f16x8*)g;

    f16x8 sv = gp[(size_t)n * F8 + c8];       // self term
    float a0[8], a1[8], a2[8], a3[8];
#pragma unroll
    for (int j = 0; j < 8; j++) {
        a0[j] = (float)sv[j];
        a1[j] = 0.f; a2[j] = 0.f; a3[j] = 0.f;
    }
    int e0 = rowptr[n], e1 = rowptr[n + 1];
    int e = e0;
    for (; e + 4 <= e1; e += 4) {
        int s0 = ssrc[e], s1 = ssrc[e + 1], s2 = ssrc[e + 2], s3 = ssrc[e + 3];
        f16x8 v0 = gp[(size_t)s0 * F8 + c8];
        f16x8 v1 = gp[(size_t)s1 * F8 + c8];
        f16x8 v2 = gp[(size_t)s2 * F8 + c8];
        f16x8 v3 = gp[(size_t)s3 * F8 + c8];
#pragma unroll
        for (int j = 0; j < 8; j++) {
            a0[j] += (float)v0[j];
            a1[j] += (float)v1[j];
            a2[j] += (float)v2[j];
            a3[j] += (float)v3[j];
        }
    }
    for (; e < e1; e++) {
        int s = ssrc[e];
        f16x8 v = gp[(size_t)s * F8 + c8];
#pragma unroll
        for (int j = 0; j < 8; j++) a0[j] += (float)v[j];
    }
    float dv = dinv[n];
    float o[8];
#pragma unroll
    for (int j = 0; j < 8; j++) {
        float s = (a0[j] + a1[j]) + (a2[j] + a3[j]);
        o[j] = s * dv + bias[c8 * 8 + j];
        if (relu) o[j] = fmaxf(o[j], 0.f);
    }
    if (writebf) {
        short8 h8, l8;
#pragma unroll
        for (int j = 0; j < 8; j++) {
            short h, l;
            split_bf16(o[j], h, l);
            h8[j] = h; l8[j] = l;
        }
        *(short8*)&oh[(size_t)n * F + c8 * 8] = h8;
        *(short8*)&ol[(size_t)n * F + c8 * 8] = l8;
    } else {
        *(float4*)&outf[(size_t)n * F + c8 * 8] =
            make_float4(o[0], o[1], o[2], o[3]);
        *(float4*)&outf[(size_t)n * F + c8 * 8 + 4] =
            make_float4(o[4], o[5], o[6], o[7]);
    }
}

// ---------------- launch ----------------

static inline size_t align256(size_t x) { return (x + 255) & ~(size_t)255; }

extern "C" void kernel_launch(void* const* d_in, const int* in_sizes, int n_in,
                              void* d_out, int out_size, void* d_ws, size_t ws_size,
                              hipStream_t stream) {
    const float* x  = (const float*)d_in[0];
    const int*   ei = (const int*)d_in[1];
    const float* W0 = (const float*)d_in[2];
    const float* b0 = (const float*)d_in[3];
    const float* W1 = (const float*)d_in[4];
    const float* b1 = (const float*)d_in[5];
    const float* W2 = (const float*)d_in[6];
    const float* b2 = (const float*)d_in[7];
    float* out = (float*)d_out;

    const int* src = ei;
    const int* dst = ei + NEDGES;

    char* w = (char*)d_ws;
    size_t off = 0;
    float* dinv   = (float*)(w + off); off = align256(off + NNODES * 4);
    int* rowptr   = (int*)(w + off);   off = align256(off + (NNODES + 1) * 4);
    int* chist    = (int*)(w + off);   off = align256(off + 256 * 4);
    int* coff     = (int*)(w + off);   off = align256(off + 256 * 4);
    int* ccur     = (int*)(w + off);   off = align256(off + 256 * 4);
    unsigned* buck = (unsigned*)(w + off); off = align256(off + (size_t)NEDGES * 4);
    int* ssrc     = (int*)(w + off);   off = align256(off + (size_t)NEDGES * 4);
    short* W0h    = (short*)(w + off); off = align256(off + 256 * 128 * 2);
    short* W0l    = (short*)(w + off); off = align256(off + 256 * 128 * 2);
    short* W1h    = (short*)(w + off); off = align256(off + 128 * 128 * 2);
    short* W1l    = (short*)(w + off); off = align256(off + 128 * 128 * 2);
    short* W2h    = (short*)(w + off); off = align256(off + 128 * 64 * 2);
    short* W2l    = (short*)(w + off); off = align256(off + 128 * 64 * 2);
    short* xh     = (short*)(w + off); off = align256(off + (size_t)NNODES * 256 * 2);
    short* xl     = (short*)(w + off); off = align256(off + (size_t)NNODES * 256 * 2);
    short* ph     = (short*)(w + off); off = align256(off + (size_t)NNODES * 128 * 2);
    short* pl     = (short*)(w + off); off = align256(off + (size_t)NNODES * 128 * 2);
    _Float16* g16 = (_Float16*)(w + off); off = align256(off + (size_t)NNODES * 128 * 2);

    // prep (k_split also zeroes chist)
    k_wprep3<<<224, 256, 0, stream>>>(W0, W0h, W0l, W1, W1h, W1l, W2, W2h, W2l);
    k_split<<<(NNODES * 32 + 255) / 256, 256, 0, stream>>>(x, xh, xl, chist,
                                                           NNODES * 32);
    // CSR via two-level radix scatter
    k_p1<<<256, 256, 0, stream>>>(dst, chist);
    k_cscan<<<1, 256, 0, stream>>>(chist, coff, ccur, rowptr);
    k_p2<<<256, 256, 0, stream>>>(src, dst, ccur, buck);
    k_p3<<<256, 256, 0, stream>>>(buck, coff, chist, rowptr, dinv, ssrc);

    const int MB = (NNODES + 63) / 64;   // 782

    // layer 0
    k_gemm2<128><<<MB, 256, 0, stream>>>(xh, xl, W0h, W0l, dinv, g16, NNODES, 256);
    k_agg<<<(NNODES * 16 + 255) / 256, 256, 0, stream>>>(g16, ssrc, rowptr, dinv, b0,
                                                         (float*)nullptr, ph, pl,
                                                         128, 4, 1, 1);
    // layer 1
    k_gemm2<128><<<MB, 256, 0, stream>>>(ph, pl, W1h, W1l, dinv, g16, NNODES, 128);
    k_agg<<<(NNODES * 16 + 255) / 256, 256, 0, stream>>>(g16, ssrc, rowptr, dinv, b1,
                                                         (float*)nullptr, ph, pl,
                                                         128, 4, 1, 1);
    // layer 2
    k_gemm2<64><<<MB, 256, 0, stream>>>(ph, pl, W2h, W2l, dinv, g16, NNODES, 128);
    k_agg<<<(NNODES * 8 + 255) / 256, 256, 0, stream>>>(g16, ssrc, rowptr, dinv, b2,
                                                        out, (short*)nullptr,
                                                        (short*)nullptr, 64, 3, 0, 0);
    (void)in_sizes; (void)n_in; (void)out_size; (void)ws_size;
}